// Round 3
// baseline (306.938 us; speedup 1.0000x reference)
//
#include <hip/hip_runtime.h>
#include <hip/hip_bf16.h>

// Fused Interaction Estimator, v3: persistent-W-in-registers, spill-fixed.
// 512 blocks x 512 threads (8 waves, 1 block/CU). Each wave owns a 32-col
// slice; W fragments for BOTH branches live in 128 VGPRs, loaded once per
// block, reused across 6 row-tiles x (g,p). Inner loop: ds_read_b128 + MFMA.
// A-tile staging is split (T14): global->regs issued early in a barrier
// interval, f32->bf16 convert + swizzled ds_write late, so HBM latency hides
// under GEMM/LN compute. 4 __syncthreads per tile.

typedef float f32x4 __attribute__((ext_vector_type(4)));
typedef short short8 __attribute__((ext_vector_type(8)));

#define D_DIM 256
#define ROWS 32
#define NW 8
#define NBLOCKS 512

__device__ __forceinline__ unsigned short f2bf(float x) {
  unsigned int u = __float_as_uint(x);
  unsigned int r = (u + 0x7FFFu + ((u >> 16) & 1u)) >> 16;
  return (unsigned short)r;
}

__device__ __forceinline__ float sigm(float x) {
  return 1.0f / (1.0f + __expf(-x));
}

// ---------------- prep: pack W (f32 [k][m] row-major) into bf16 MFMA B-fragment order ----
// chunk = (c*8 + t)*64 + l holds 8 bf16: B[k = t*32 + (l>>4)*8 + j][m = c*16 + (l&15)]
__global__ __launch_bounds__(256) void pack_w_kernel(const float* __restrict__ Wg,
                                                     const float* __restrict__ Wp,
                                                     unsigned short* __restrict__ outp) {
  int b = blockIdx.x;
  const float* W = (b < 32) ? Wg : Wp;
  unsigned short* o = outp + (b < 32 ? 0 : 65536);
  int chunk = (b & 31) * 256 + threadIdx.x;
  int c = chunk >> 9;
  int rest = chunk & 511;
  int t = rest >> 6;
  int l = rest & 63;
  int m = c * 16 + (l & 15);
  int kb = t * 32 + ((l >> 4) << 3);
  short8 v;
#pragma unroll
  for (int j = 0; j < 8; ++j) v[j] = (short)f2bf(W[(kb + j) * 256 + m]);
  *(short8*)(o + (size_t)chunk * 8) = v;
}

// ---------------- main fused kernel ----------------

__device__ __forceinline__ short8 readA(const unsigned short* smA, int rt, int t, int lane) {
  int row = rt * 16 + (lane & 15);
  int off = (row * 512 + t * 64 + ((lane >> 4) << 4)) ^ ((row & 7) << 4);
  return *(const short8*)((const char*)smA + off);
}

// split staging: issue loads (early) / convert + swizzled LDS write (late)
__device__ __forceinline__ void stageIssue(const float* __restrict__ src, int tid, float4 v[4]) {
  const float4* s4 = (const float4*)src;
#pragma unroll
  for (int it = 0; it < 4; ++it) v[it] = s4[it * 512 + tid];
}

__device__ __forceinline__ void stageWrite(const float4 v[4], unsigned short* smA, int tid) {
#pragma unroll
  for (int it = 0; it < 4; ++it) {
    int idx = it * 512 + tid;
    int row = idx >> 6;
    int k4 = (idx & 63) << 2;
    ushort4 h;
    h.x = f2bf(v[it].x); h.y = f2bf(v[it].y); h.z = f2bf(v[it].z); h.w = f2bf(v[it].w);
    int off = (row * 512 + k4 * 2) ^ ((row & 7) << 4);
    *(ushort4*)((char*)smA + off) = h;
  }
}

__device__ __forceinline__ void gemm2(f32x4 acc[2][2], const unsigned short* smA,
                                      const short8 wf[2][8], int lane) {
#pragma unroll
  for (int t = 0; t < 8; ++t) {
    short8 a0 = readA(smA, 0, t, lane);
    short8 a1 = readA(smA, 1, t, lane);
#pragma unroll
    for (int c = 0; c < 2; ++c) {
      acc[0][c] = __builtin_amdgcn_mfma_f32_16x16x32_bf16(a0, wf[c][t], acc[0][c], 0, 0, 0);
      acc[1][c] = __builtin_amdgcn_mfma_f32_16x16x32_bf16(a1, wf[c][t], acc[1][c], 0, 0, 0);
    }
  }
}

__device__ __forceinline__ void statsPhase(f32x4 acc[2][2], const float* __restrict__ bias,
                                           float smSum[NW][32], float smSq[NW][32],
                                           int lane, int w) {
  float bv[2];
#pragma unroll
  for (int c = 0; c < 2; ++c) bv[c] = bias[w * 32 + c * 16 + (lane & 15)];
#pragma unroll
  for (int rt = 0; rt < 2; ++rt) {
#pragma unroll
    for (int r = 0; r < 4; ++r) {
      float s = 0.f, qq = 0.f;
#pragma unroll
      for (int c = 0; c < 2; ++c) {
        float y = acc[rt][c][r] + bv[c];
        acc[rt][c][r] = y;
        s += y; qq += y * y;
      }
#pragma unroll
      for (int m = 1; m < 16; m <<= 1) {
        s += __shfl_xor(s, m, 64);
        qq += __shfl_xor(qq, m, 64);
      }
      if ((lane & 15) == 0) {
        int row = rt * 16 + ((lane >> 4) << 2) + r;
        smSum[w][row] = s;
        smSq[w][row] = qq;
      }
    }
  }
}

__device__ __forceinline__ void applyPhase(f32x4 acc[2][2], f32x4 outAl[2][2],
                                           const float* __restrict__ gam, const float* __restrict__ bet,
                                           const float* __restrict__ wa,
                                           const float smSum[NW][32], const float smSq[NW][32],
                                           float smRed[NW][32], int lane, int w) {
  int cb = w * 32 + (lane & 15);
  float gv[2], tv[2], wv[2];
#pragma unroll
  for (int c = 0; c < 2; ++c) {
    gv[c] = gam[cb + c * 16];
    tv[c] = bet[cb + c * 16];
    wv[c] = wa[cb + c * 16];
  }
#pragma unroll
  for (int rt = 0; rt < 2; ++rt) {
#pragma unroll
    for (int r = 0; r < 4; ++r) {
      int row = rt * 16 + ((lane >> 4) << 2) + r;
      float s = 0.f, qq = 0.f;
#pragma unroll
      for (int k = 0; k < NW; ++k) { s += smSum[k][row]; qq += smSq[k][row]; }
      float mu = s * (1.0f / 256.0f);
      float var = qq * (1.0f / 256.0f) - mu * mu;
      var = fmaxf(var, 0.0f);
      float rs = rsqrtf(var + 1e-5f);
      float dp = 0.f;
#pragma unroll
      for (int c = 0; c < 2; ++c) {
        float a = (acc[rt][c][r] - mu) * rs * gv[c] + tv[c];
        a = fmaxf(a, 0.0f);
        outAl[rt][c][r] = a;
        dp += a * wv[c];
      }
#pragma unroll
      for (int m = 1; m < 16; m <<= 1) dp += __shfl_xor(dp, m, 64);
      if ((lane & 15) == 0) smRed[w][row] = dp;
    }
  }
}

__global__ __launch_bounds__(512) void fused_main(
    const float* __restrict__ gfeat, const float* __restrict__ pfeat,
    const float* __restrict__ bg, const float* __restrict__ glng, const float* __restrict__ glnb,
    const float* __restrict__ bp, const float* __restrict__ plng, const float* __restrict__ plnb,
    const float* __restrict__ wag, const float* __restrict__ bag,
    const float* __restrict__ wap, const float* __restrict__ bap,
    const unsigned short* __restrict__ wpk,
    float* __restrict__ outp, int tilesPerBlock)
{
  __shared__ unsigned short bufA[2][ROWS * D_DIM];   // 2 x 16 KB: [0]=g, [1]=p
  __shared__ float smSum[NW][32];
  __shared__ float smSq[NW][32];
  __shared__ float smRedG[NW][32];
  __shared__ float smRedP[NW][32];

  const int tid = threadIdx.x;
  const int lane = tid & 63;
  const int w = tid >> 6;

  const int tile0 = blockIdx.x * tilesPerBlock;
  const float* gsrc = gfeat + (size_t)tile0 * ROWS * D_DIM;
  const float* psrc = pfeat + (size_t)tile0 * ROWS * D_DIM;
  float* obase = outp + (size_t)tile0 * ROWS * D_DIM;

  // prologue: issue g(0) loads, then persistent W fragments (128 VGPRs), then write g(0)
  float4 sv[4];
  stageIssue(gsrc, tid, sv);

  short8 wfg[2][8], wfp[2][8];
  {
    const short8* wp8 = (const short8*)wpk;
#pragma unroll
    for (int c = 0; c < 2; ++c)
#pragma unroll
      for (int t = 0; t < 8; ++t) {
        int idx = (((w * 2 + c) * 8 + t) << 6) + lane;
        wfg[c][t] = wp8[idx];
        wfp[c][t] = wp8[8192 + idx];
      }
  }
  stageWrite(sv, bufA[0], tid);
  __syncthreads();

  const float vbag = bag[0], vbap = bap[0];

  for (int i = 0; i < tilesPerBlock; ++i) {
    const size_t tb = (size_t)i * ROWS * D_DIM;

    // ---- interval A (ends #1): p(i) loads issue early; gemm g; stats; p write late
    stageIssue(psrc + tb, tid, sv);

    f32x4 accG[2][2];
#pragma unroll
    for (int rt = 0; rt < 2; ++rt)
#pragma unroll
      for (int c = 0; c < 2; ++c) accG[rt][c] = {0.f, 0.f, 0.f, 0.f};
    gemm2(accG, bufA[0], wfg, lane);
    statsPhase(accG, bg, smSum, smSq, lane, w);

    stageWrite(sv, bufA[1], tid);           // p(i) -> buf1 (read next interval)
    __syncthreads();   // #1: statsG + p(i) visible; buf0 reads done

    // ---- interval B (ends #2): g(i+1) loads issue early; LN g; gemm p
    float4 gv4[4];
    if (i + 1 < tilesPerBlock) stageIssue(gsrc + tb + ROWS * D_DIM, tid, gv4);

    f32x4 alignG[2][2];
    applyPhase(accG, alignG, glng, glnb, wap, smSum, smSq, smRedG, lane, w);

    f32x4 accP[2][2];
#pragma unroll
    for (int rt = 0; rt < 2; ++rt)
#pragma unroll
      for (int c = 0; c < 2; ++c) accP[rt][c] = {0.f, 0.f, 0.f, 0.f};
    gemm2(accP, bufA[1], wfp, lane);
    __syncthreads();   // #2: applyG smSum reads done; smRedG visible; buf1 reads done

    // ---- interval C (ends #3): stats p; g(i+1) write late
    statsPhase(accP, bp, smSum, smSq, lane, w);
    if (i + 1 < tilesPerBlock) stageWrite(gv4, bufA[0], tid);   // g(i+1) -> buf0
    __syncthreads();   // #3: statsP + g(i+1) visible

    // ---- interval D (ends #4): LN p
    applyPhase(accP, accP, plng, plnb, wag, smSum, smSq, smRedP, lane, w);
    __syncthreads();   // #4: smRedP visible; applyP smSum reads done

    // ---- fusion + store (same interval as next iter's interval A)
#pragma unroll
    for (int rt = 0; rt < 2; ++rt) {
#pragma unroll
      for (int r = 0; r < 4; ++r) {
        int row = rt * 16 + ((lane >> 4) << 2) + r;
        float gr = 0.f, pr = 0.f;
#pragma unroll
        for (int k = 0; k < NW; ++k) { gr += smRedG[k][row]; pr += smRedP[k][row]; }
        float* orow = obase + tb + (size_t)row * D_DIM + w * 32 + (lane & 15);
#pragma unroll
        for (int c = 0; c < 2; ++c) {
          float ga = alignG[rt][c][r];
          float pa = accP[rt][c][r];
          float geno = sigm(ga * pr + vbag);
          float path = sigm(pa * gr + vbap);
          orow[c * 16] = pa * path + ga * geno;
        }
      }
    }
    // hazards across the loop seam:
    //  - smSum rewritten by statsG(i+1) only after #4 (program order; applyP reads done at #4)
    //  - smRedG/P read by fusion before next #1; rewritten after next #1/#3
    //  - buf0 (g(i+1)) written in interval C, read by gemm g after #4
    //  - buf1 rewritten in next interval A, reads done at #2
  }
}

extern "C" void kernel_launch(void* const* d_in, const int* in_sizes, int n_in,
                              void* d_out, int out_size, void* d_ws, size_t ws_size,
                              hipStream_t stream) {
  const float* gfeat = (const float*)d_in[0];
  const float* pfeat = (const float*)d_in[1];
  const float* Wg   = (const float*)d_in[2];
  const float* bg   = (const float*)d_in[3];
  const float* glng = (const float*)d_in[4];
  const float* glnb = (const float*)d_in[5];
  const float* Wp   = (const float*)d_in[6];
  const float* bp   = (const float*)d_in[7];
  const float* plng = (const float*)d_in[8];
  const float* plnb = (const float*)d_in[9];
  const float* wag  = (const float*)d_in[10];
  const float* bag  = (const float*)d_in[11];
  const float* wap  = (const float*)d_in[12];
  const float* bap  = (const float*)d_in[13];
  float* outp = (float*)d_out;
  unsigned short* wpk = (unsigned short*)d_ws;

  hipLaunchKernelGGL(pack_w_kernel, dim3(64), dim3(256), 0, stream, Wg, Wp, wpk);

  int nrows = in_sizes[0] / D_DIM;          // 98304
  int tiles = nrows / ROWS;                 // 3072
  int tilesPerBlock = tiles / NBLOCKS;      // 6
  hipLaunchKernelGGL(fused_main, dim3(NBLOCKS), dim3(512), 0, stream,
                     gfeat, pfeat, bg, glng, glnb, bp, plng, plnb,
                     wag, bag, wap, bap, wpk, outp, tilesPerBlock);
}

// Round 4
// 208.453 us; speedup vs baseline: 1.4725x; 1.4725x over previous
//
#include <hip/hip_runtime.h>
#include <hip/hip_bf16.h>

// Fused Interaction Estimator, v4: v1 structure + deep load front-loading.
// 1536 blocks x 512 threads (8 waves), 2 row-tiles (32 rows) per block.
// A staged bf16 in LDS (XOR swizzle); B (W) fragments read from L2-cached
// global inside the gemm (NOT register-persistent -- the 128-VGPR cap made
// that spill in v2/v3). Split staging: next tile's global loads issue 2-3
// barrier intervals before their LDS write, so HBM latency hides under
// GEMM/LN compute and outstanding-bytes stay high (MLP fix).

typedef float f32x4 __attribute__((ext_vector_type(4)));
typedef short short8 __attribute__((ext_vector_type(8)));

#define D_DIM 256
#define ROWS 32
#define NW 8
#define TPB 2          // tiles per block

__device__ __forceinline__ unsigned short f2bf(float x) {
  unsigned int u = __float_as_uint(x);
  unsigned int r = (u + 0x7FFFu + ((u >> 16) & 1u)) >> 16;
  return (unsigned short)r;
}

__device__ __forceinline__ float sigm(float x) {
  return 1.0f / (1.0f + __expf(-x));
}

// ---------------- prep: pack W (f32 [k][m] row-major) into bf16 MFMA B-fragment order ----
// chunk = (c*8 + t)*64 + l holds 8 bf16: B[k = t*32 + (l>>4)*8 + j][m = c*16 + (l&15)]
__global__ __launch_bounds__(256) void pack_w_kernel(const float* __restrict__ Wg,
                                                     const float* __restrict__ Wp,
                                                     unsigned short* __restrict__ outp) {
  int b = blockIdx.x;
  const float* W = (b < 32) ? Wg : Wp;
  unsigned short* o = outp + (b < 32 ? 0 : 65536);
  int chunk = (b & 31) * 256 + threadIdx.x;
  int c = chunk >> 9;
  int rest = chunk & 511;
  int t = rest >> 6;
  int l = rest & 63;
  int m = c * 16 + (l & 15);
  int kb = t * 32 + ((l >> 4) << 3);
  short8 v;
#pragma unroll
  for (int j = 0; j < 8; ++j) v[j] = (short)f2bf(W[(kb + j) * 256 + m]);
  *(short8*)(o + (size_t)chunk * 8) = v;
}

// ---------------- main fused kernel ----------------

__device__ __forceinline__ short8 readA(const unsigned short* smA, int rt, int t, int lane) {
  int row = rt * 16 + (lane & 15);
  int off = (row * 512 + t * 64 + ((lane >> 4) << 4)) ^ ((row & 7) << 4);
  return *(const short8*)((const char*)smA + off);
}

// split staging for 512 threads: 4 float4 per thread
__device__ __forceinline__ void stageIssue(const float* __restrict__ src, int tid, float4 v[4]) {
  const float4* s4 = (const float4*)src;
#pragma unroll
  for (int it = 0; it < 4; ++it) v[it] = s4[it * 512 + tid];
}

__device__ __forceinline__ void stageWrite(const float4 v[4], unsigned short* smA, int tid) {
#pragma unroll
  for (int it = 0; it < 4; ++it) {
    int idx = it * 512 + tid;
    int row = idx >> 6;
    int k4 = (idx & 63) << 2;
    ushort4 h;
    h.x = f2bf(v[it].x); h.y = f2bf(v[it].y); h.z = f2bf(v[it].z); h.w = f2bf(v[it].w);
    int off = (row * 512 + k4 * 2) ^ ((row & 7) << 4);
    *(ushort4*)((char*)smA + off) = h;
  }
}

// each wave owns 32 cols (2 ct tiles); B-frags streamed from global (L2-hot)
__device__ __forceinline__ void gemm2(f32x4 acc[2][2], const unsigned short* smA,
                                      const short8* __restrict__ wb, int lane, int w) {
  const int bbase = w * 1024 + lane;   // (w*2+c)*8*64 = w*1024 + c*512
#pragma unroll
  for (int t = 0; t < 8; ++t) {
    short8 a0 = readA(smA, 0, t, lane);
    short8 a1 = readA(smA, 1, t, lane);
#pragma unroll
    for (int c = 0; c < 2; ++c) {
      short8 bfr = wb[bbase + c * 512 + t * 64];
      acc[0][c] = __builtin_amdgcn_mfma_f32_16x16x32_bf16(a0, bfr, acc[0][c], 0, 0, 0);
      acc[1][c] = __builtin_amdgcn_mfma_f32_16x16x32_bf16(a1, bfr, acc[1][c], 0, 0, 0);
    }
  }
}

__device__ __forceinline__ void statsPhase(f32x4 acc[2][2], const float* __restrict__ bias,
                                           float smSum[NW][32], float smSq[NW][32],
                                           int lane, int w) {
  float bv[2];
#pragma unroll
  for (int c = 0; c < 2; ++c) bv[c] = bias[w * 32 + c * 16 + (lane & 15)];
#pragma unroll
  for (int rt = 0; rt < 2; ++rt) {
#pragma unroll
    for (int r = 0; r < 4; ++r) {
      float s = 0.f, qq = 0.f;
#pragma unroll
      for (int c = 0; c < 2; ++c) {
        float y = acc[rt][c][r] + bv[c];
        acc[rt][c][r] = y;
        s += y; qq += y * y;
      }
#pragma unroll
      for (int m = 1; m < 16; m <<= 1) {
        s += __shfl_xor(s, m, 64);
        qq += __shfl_xor(qq, m, 64);
      }
      if ((lane & 15) == 0) {
        int row = rt * 16 + ((lane >> 4) << 2) + r;
        smSum[w][row] = s;
        smSq[w][row] = qq;
      }
    }
  }
}

__device__ __forceinline__ void applyPhase(f32x4 acc[2][2], f32x4 outAl[2][2],
                                           const float* __restrict__ gam, const float* __restrict__ bet,
                                           const float* __restrict__ wa,
                                           const float smSum[NW][32], const float smSq[NW][32],
                                           float smRed[NW][32], int lane, int w) {
  int cb = w * 32 + (lane & 15);
  float gv[2], tv[2], wv[2];
#pragma unroll
  for (int c = 0; c < 2; ++c) {
    gv[c] = gam[cb + c * 16];
    tv[c] = bet[cb + c * 16];
    wv[c] = wa[cb + c * 16];
  }
#pragma unroll
  for (int rt = 0; rt < 2; ++rt) {
#pragma unroll
    for (int r = 0; r < 4; ++r) {
      int row = rt * 16 + ((lane >> 4) << 2) + r;
      float s = 0.f, qq = 0.f;
#pragma unroll
      for (int k = 0; k < NW; ++k) { s += smSum[k][row]; qq += smSq[k][row]; }
      float mu = s * (1.0f / 256.0f);
      float var = qq * (1.0f / 256.0f) - mu * mu;
      var = fmaxf(var, 0.0f);
      float rs = rsqrtf(var + 1e-5f);
      float dp = 0.f;
#pragma unroll
      for (int c = 0; c < 2; ++c) {
        float a = (acc[rt][c][r] - mu) * rs * gv[c] + tv[c];
        a = fmaxf(a, 0.0f);
        outAl[rt][c][r] = a;
        dp += a * wv[c];
      }
#pragma unroll
      for (int m = 1; m < 16; m <<= 1) dp += __shfl_xor(dp, m, 64);
      if ((lane & 15) == 0) smRed[w][row] = dp;
    }
  }
}

__global__ __launch_bounds__(512) void fused_main(
    const float* __restrict__ gfeat, const float* __restrict__ pfeat,
    const float* __restrict__ bg, const float* __restrict__ glng, const float* __restrict__ glnb,
    const float* __restrict__ bp, const float* __restrict__ plng, const float* __restrict__ plnb,
    const float* __restrict__ wag, const float* __restrict__ bag,
    const float* __restrict__ wap, const float* __restrict__ bap,
    const unsigned short* __restrict__ wpk,
    float* __restrict__ outp)
{
  __shared__ unsigned short bufA[ROWS * D_DIM];   // 16 KB, g then p per tile
  __shared__ float smSum[NW][32];
  __shared__ float smSq[NW][32];
  __shared__ float smRedG[NW][32];
  __shared__ float smRedP[NW][32];

  const int tid = threadIdx.x;
  const int lane = tid & 63;
  const int w = tid >> 6;

  const size_t TILE = (size_t)ROWS * D_DIM;
  const float* gsrc = gfeat + (size_t)blockIdx.x * TPB * TILE;
  const float* psrc = pfeat + (size_t)blockIdx.x * TPB * TILE;
  float* obase = outp + (size_t)blockIdx.x * TPB * TILE;

  const short8* wbg = (const short8*)wpk;
  const short8* wbp = (const short8*)(wpk + 65536);

  // front-load BOTH first tiles' loads (32 regs total in flight)
  float4 svG[4], svP[4];
  stageIssue(gsrc, tid, svG);
  stageIssue(psrc, tid, svP);

  const float vbag = bag[0], vbap = bap[0];

#pragma unroll
  for (int i = 0; i < TPB; ++i) {
    const size_t tb = (size_t)i * TILE;

    stageWrite(svG, bufA, tid);
    __syncthreads();   // #1: g(i) staged

    f32x4 accG[2][2];
#pragma unroll
    for (int rt = 0; rt < 2; ++rt)
#pragma unroll
      for (int c = 0; c < 2; ++c) accG[rt][c] = {0.f, 0.f, 0.f, 0.f};
    gemm2(accG, bufA, wbg, lane, w);
    statsPhase(accG, bg, smSum, smSq, lane, w);
    __syncthreads();   // #2: statsG visible; bufA g-reads done

    if (i + 1 < TPB) stageIssue(gsrc + tb + TILE, tid, svG);   // g(i+1) issues; covered by p-phase

    f32x4 alignG[2][2];
    applyPhase(accG, alignG, glng, glnb, wap, smSum, smSq, smRedG, lane, w);
    stageWrite(svP, bufA, tid);
    __syncthreads();   // #3: p(i) staged; smRedG visible; applyG smSum reads done

    f32x4 accP[2][2];
#pragma unroll
    for (int rt = 0; rt < 2; ++rt)
#pragma unroll
      for (int c = 0; c < 2; ++c) accP[rt][c] = {0.f, 0.f, 0.f, 0.f};
    gemm2(accP, bufA, wbp, lane, w);
    statsPhase(accP, bp, smSum, smSq, lane, w);   // smSum overwrite: applyG reads ended at #3
    __syncthreads();   // #4: statsP visible; bufA p-reads done

    if (i + 1 < TPB) stageIssue(psrc + tb + TILE, tid, svP);   // p(i+1) issues; covered by g(i+1) phase

    applyPhase(accP, accP, plng, plnb, wag, smSum, smSq, smRedP, lane, w);
    __syncthreads();   // #5: smRedP visible; applyP smSum reads done

    // fusion + store
#pragma unroll
    for (int rt = 0; rt < 2; ++rt) {
#pragma unroll
      for (int r = 0; r < 4; ++r) {
        int row = rt * 16 + ((lane >> 4) << 2) + r;
        float gr = 0.f, pr = 0.f;
#pragma unroll
        for (int k = 0; k < NW; ++k) { gr += smRedG[k][row]; pr += smRedP[k][row]; }
        float* orow = obase + tb + (size_t)row * D_DIM + w * 32 + (lane & 15);
#pragma unroll
        for (int c = 0; c < 2; ++c) {
          float ga = alignG[rt][c][r];
          float pa = accP[rt][c][r];
          float geno = sigm(ga * pr + vbag);
          float path = sigm(pa * gr + vbap);
          orow[c * 16] = pa * path + ga * geno;
        }
      }
    }
    // loop-seam hazards:
    //  - next stageWrite(svG->bufA): bufA p-reads ended at #4, we're past #5      [safe]
    //  - statsG(i+1) rewrites smSum after next #1; applyP reads ended at #5       [safe]
    //  - applyG(i+1) rewrites smRedG after next #2; fusion(i) reads finish before
    //    any wave passes next #1 (barrier collectivity)                           [safe]
  }
}

extern "C" void kernel_launch(void* const* d_in, const int* in_sizes, int n_in,
                              void* d_out, int out_size, void* d_ws, size_t ws_size,
                              hipStream_t stream) {
  const float* gfeat = (const float*)d_in[0];
  const float* pfeat = (const float*)d_in[1];
  const float* Wg   = (const float*)d_in[2];
  const float* bg   = (const float*)d_in[3];
  const float* glng = (const float*)d_in[4];
  const float* glnb = (const float*)d_in[5];
  const float* Wp   = (const float*)d_in[6];
  const float* bp   = (const float*)d_in[7];
  const float* plng = (const float*)d_in[8];
  const float* plnb = (const float*)d_in[9];
  const float* wag  = (const float*)d_in[10];
  const float* bag  = (const float*)d_in[11];
  const float* wap  = (const float*)d_in[12];
  const float* bap  = (const float*)d_in[13];
  float* outp = (float*)d_out;
  unsigned short* wpk = (unsigned short*)d_ws;

  hipLaunchKernelGGL(pack_w_kernel, dim3(64), dim3(256), 0, stream, Wg, Wp, wpk);

  int nrows = in_sizes[0] / D_DIM;          // 98304
  int nblocks = nrows / (ROWS * TPB);       // 1536
  hipLaunchKernelGGL(fused_main, dim3(nblocks), dim3(512), 0, stream,
                     gfeat, pfeat, bg, glng, glnb, bp, plng, plnb,
                     wag, bag, wap, bap, wpk, outp);
}